// Round 1
// baseline (228.614 us; speedup 1.0000x reference)
//
#include <hip/hip_runtime.h>

// Inverse 2D Haar wavelet (2-tap, stride-2 conv_transpose, depthwise).
// x:   [B=8, 4*C=256, H=128, W=128] fp32, subbands [LL | HL | LH | HH]
// out: [B=8, C=64, 2H=256, 2W=256] fp32
//
// Each input (h,w) maps to exactly one 2x2 output block:
//   out[2h  ][2w  ] = 0.5*(LL + LH + HL + HH)
//   out[2h  ][2w+1] = 0.5*(LL - LH + HL - HH)
//   out[2h+1][2w  ] = 0.5*(LL + LH - HL - HH)
//   out[2h+1][2w+1] = 0.5*(LL - LH - HL + HH)

__global__ __launch_bounds__(256) void iwt_haar_kernel(const float* __restrict__ x,
                                                       float* __restrict__ out) {
    constexpr int W = 128, H = 128, C = 64;
    constexpr int W4 = W / 4;                     // 32 float4 per input row
    constexpr long long PLANE = (long long)H * W; // 16384

    const long long idx = (long long)blockIdx.x * blockDim.x + threadIdx.x;
    const int w4 = (int)(idx & (W4 - 1));         // 5 bits
    const int h  = (int)((idx >> 5) & (H - 1));   // 7 bits
    const int c  = (int)((idx >> 12) & (C - 1));  // 6 bits
    const int b  = (int)(idx >> 18);              // 3 bits

    const float* p = x + ((long long)b * 4 * C + c) * PLANE
                       + (long long)h * W + (long long)w4 * 4;
    const float4 ll = *(const float4*)(p);
    const float4 hl = *(const float4*)(p + (long long)1 * C * PLANE);
    const float4 lh = *(const float4*)(p + (long long)2 * C * PLANE);
    const float4 hh = *(const float4*)(p + (long long)3 * C * PLANE);

    // width-pass butterflies
    float4 s0, d0, s1, d1;
    s0.x = ll.x + lh.x; s0.y = ll.y + lh.y; s0.z = ll.z + lh.z; s0.w = ll.w + lh.w;
    d0.x = ll.x - lh.x; d0.y = ll.y - lh.y; d0.z = ll.z - lh.z; d0.w = ll.w - lh.w;
    s1.x = hl.x + hh.x; s1.y = hl.y + hh.y; s1.z = hl.z + hh.z; s1.w = hl.w + hh.w;
    d1.x = hl.x - hh.x; d1.y = hl.y - hh.y; d1.z = hl.z - hh.z; d1.w = hl.w - hh.w;

    // height-pass butterflies, interleave even/odd columns
    float4 r0a, r0b, r1a, r1b;
    r0a.x = 0.5f * (s0.x + s1.x);
    r0a.y = 0.5f * (d0.x + d1.x);
    r0a.z = 0.5f * (s0.y + s1.y);
    r0a.w = 0.5f * (d0.y + d1.y);
    r0b.x = 0.5f * (s0.z + s1.z);
    r0b.y = 0.5f * (d0.z + d1.z);
    r0b.z = 0.5f * (s0.w + s1.w);
    r0b.w = 0.5f * (d0.w + d1.w);

    r1a.x = 0.5f * (s0.x - s1.x);
    r1a.y = 0.5f * (d0.x - d1.x);
    r1a.z = 0.5f * (s0.y - s1.y);
    r1a.w = 0.5f * (d0.y - d1.y);
    r1b.x = 0.5f * (s0.z - s1.z);
    r1b.y = 0.5f * (d0.z - d1.z);
    r1b.z = 0.5f * (s0.w - s1.w);
    r1b.w = 0.5f * (d0.w - d1.w);

    constexpr int OW = 2 * W;  // 256
    float* q = out + ((long long)b * C + c) * (2LL * H * OW)
                   + (long long)(2 * h) * OW + (long long)w4 * 8;
    *(float4*)(q)          = r0a;
    *(float4*)(q + 4)      = r0b;
    *(float4*)(q + OW)     = r1a;
    *(float4*)(q + OW + 4) = r1b;
}

extern "C" void kernel_launch(void* const* d_in, const int* in_sizes, int n_in,
                              void* d_out, int out_size, void* d_ws, size_t ws_size,
                              hipStream_t stream) {
    const float* x = (const float*)d_in[0];
    float* out = (float*)d_out;

    // total threads = 8 * 64 * 128 * 32 = 2,097,152
    const long long total = 8LL * 64 * 128 * 32;
    const int block = 256;
    const int grid = (int)(total / block);  // 8192
    iwt_haar_kernel<<<grid, block, 0, stream>>>(x, out);
}

// Round 2
// 224.326 us; speedup vs baseline: 1.0191x; 1.0191x over previous
//
#include <hip/hip_runtime.h>

// Inverse 2D Haar wavelet (2-tap, stride-2 conv_transpose, depthwise).
// x:   [B=8, 4*C=256, H=128, W=128] fp32, subbands [LL | HL | LH | HH]
// out: [B=8, C=64, 2H=256, 2W=256] fp32
//
// Each input (h,w) maps to exactly one 2x2 output block:
//   out[2h  ][2w  ] = 0.5*(LL + LH + HL + HH)
//   out[2h  ][2w+1] = 0.5*(LL - LH + HL - HH)
//   out[2h+1][2w  ] = 0.5*(LL + LH - HL - HH)
//   out[2h+1][2w+1] = 0.5*(LL - LH - HL + HH)
//
// R1 layout: thread handles 2 input cols -> 4 output cols.
//   loads : float2/subband, lanes contiguous (512B/wave/instr)
//   stores: one float4 per output row, lanes contiguous (1KB/wave/instr,
//           full 64B lines -> no partial-line RMW in L2)

__global__ __launch_bounds__(256) void iwt_haar_kernel(const float* __restrict__ x,
                                                       float* __restrict__ out) {
    constexpr int W = 128, H = 128, C = 64;
    constexpr int W2 = W / 2;                      // 64 float2 per input row
    constexpr long long PLANE = (long long)H * W;  // 16384
    constexpr long long CP = (long long)C * PLANE; // subband-group stride

    const long long idx = (long long)blockIdx.x * blockDim.x + threadIdx.x;
    const int w2 = (int)(idx & (W2 - 1));          // 6 bits
    const int h  = (int)((idx >> 6) & (H - 1));    // 7 bits
    const int c  = (int)((idx >> 13) & (C - 1));   // 6 bits
    const int b  = (int)(idx >> 19);               // 3 bits

    const float* p = x + ((long long)b * 4 * C + c) * PLANE
                       + (long long)h * W + (long long)w2 * 2;
    const float2 ll = *(const float2*)(p);
    const float2 hl = *(const float2*)(p + 1 * CP);
    const float2 lh = *(const float2*)(p + 2 * CP);
    const float2 hh = *(const float2*)(p + 3 * CP);

    // width-pass butterflies (2 columns)
    const float s0x = ll.x + lh.x, d0x = ll.x - lh.x;
    const float s0y = ll.y + lh.y, d0y = ll.y - lh.y;
    const float s1x = hl.x + hh.x, d1x = hl.x - hh.x;
    const float s1y = hl.y + hh.y, d1y = hl.y - hh.y;

    // height-pass butterflies, interleaved even/odd output columns
    float4 r0, r1;
    r0.x = 0.5f * (s0x + s1x);
    r0.y = 0.5f * (d0x + d1x);
    r0.z = 0.5f * (s0y + s1y);
    r0.w = 0.5f * (d0y + d1y);
    r1.x = 0.5f * (s0x - s1x);
    r1.y = 0.5f * (d0x - d1x);
    r1.z = 0.5f * (s0y - s1y);
    r1.w = 0.5f * (d0y - d1y);

    constexpr int OW = 2 * W;                        // 256
    constexpr long long OPLANE = 2LL * H * OW;       // 65536
    float* q = out + ((long long)b * C + c) * OPLANE
                   + (long long)(2 * h) * OW + (long long)w2 * 4;
    *(float4*)(q)      = r0;
    *(float4*)(q + OW) = r1;
}

extern "C" void kernel_launch(void* const* d_in, const int* in_sizes, int n_in,
                              void* d_out, int out_size, void* d_ws, size_t ws_size,
                              hipStream_t stream) {
    const float* x = (const float*)d_in[0];
    float* out = (float*)d_out;

    // total threads = 8 * 64 * 128 * 64 = 4,194,304
    const long long total = 8LL * 64 * 128 * 64;
    const int block = 256;
    const int grid = (int)(total / block);  // 16384
    iwt_haar_kernel<<<grid, block, 0, stream>>>(x, out);
}

// Round 4
// 220.412 us; speedup vs baseline: 1.0372x; 1.0178x over previous
//
#include <hip/hip_runtime.h>

// Inverse 2D Haar wavelet (2-tap, stride-2 conv_transpose, depthwise).
// x:   [B=8, 4*C=256, H=128, W=128] fp32, subbands [LL | HL | LH | HH]
// out: [B=8, C=64, 2H=256, 2W=256] fp32
//
//   out[2h  ][2w  ] = 0.5*(LL + LH + HL + HH)
//   out[2h  ][2w+1] = 0.5*(LL - LH + HL - HH)
//   out[2h+1][2w  ] = 0.5*(LL + LH - HL - HH)
//   out[2h+1][2w+1] = 0.5*(LL - LH - HL + HH)
//
// R3: R2 retry — nontemporal builtins need NATIVE clang vector types, not
// HIP_vector_type structs. Theory unchanged: harness's 512MB 0xAA poison
// leaves dirty lines in MALL; our allocating traffic forced those evictions
// to HBM inside our window. nt streams are non-allocating.

typedef float vf2 __attribute__((ext_vector_type(2)));
typedef float vf4 __attribute__((ext_vector_type(4)));

__global__ __launch_bounds__(256) void iwt_haar_kernel(const float* __restrict__ x,
                                                       float* __restrict__ out) {
    constexpr int W = 128, H = 128, C = 64;
    constexpr int W2 = W / 2;                      // 64 vf2 per input row
    constexpr long long PLANE = (long long)H * W;  // 16384
    constexpr long long CP = (long long)C * PLANE; // subband-group stride

    const long long idx = (long long)blockIdx.x * blockDim.x + threadIdx.x;
    const int w2 = (int)(idx & (W2 - 1));          // 6 bits
    const int h  = (int)((idx >> 6) & (H - 1));    // 7 bits
    const int c  = (int)((idx >> 13) & (C - 1));   // 6 bits
    const int b  = (int)(idx >> 19);               // 3 bits

    const float* p = x + ((long long)b * 4 * C + c) * PLANE
                       + (long long)h * W + (long long)w2 * 2;
    const vf2 ll = __builtin_nontemporal_load((const vf2*)(p));
    const vf2 hl = __builtin_nontemporal_load((const vf2*)(p + 1 * CP));
    const vf2 lh = __builtin_nontemporal_load((const vf2*)(p + 2 * CP));
    const vf2 hh = __builtin_nontemporal_load((const vf2*)(p + 3 * CP));

    // width-pass butterflies (2 columns)
    const float s0x = ll.x + lh.x, d0x = ll.x - lh.x;
    const float s0y = ll.y + lh.y, d0y = ll.y - lh.y;
    const float s1x = hl.x + hh.x, d1x = hl.x - hh.x;
    const float s1y = hl.y + hh.y, d1y = hl.y - hh.y;

    // height-pass butterflies, interleaved even/odd output columns
    vf4 r0, r1;
    r0.x = 0.5f * (s0x + s1x);
    r0.y = 0.5f * (d0x + d1x);
    r0.z = 0.5f * (s0y + s1y);
    r0.w = 0.5f * (d0y + d1y);
    r1.x = 0.5f * (s0x - s1x);
    r1.y = 0.5f * (d0x - d1x);
    r1.z = 0.5f * (s0y - s1y);
    r1.w = 0.5f * (d0y - d1y);

    constexpr int OW = 2 * W;                        // 256
    constexpr long long OPLANE = 2LL * H * OW;       // 65536
    float* q = out + ((long long)b * C + c) * OPLANE
                   + (long long)(2 * h) * OW + (long long)w2 * 4;
    __builtin_nontemporal_store(r0, (vf4*)(q));
    __builtin_nontemporal_store(r1, (vf4*)(q + OW));
}

extern "C" void kernel_launch(void* const* d_in, const int* in_sizes, int n_in,
                              void* d_out, int out_size, void* d_ws, size_t ws_size,
                              hipStream_t stream) {
    const float* x = (const float*)d_in[0];
    float* out = (float*)d_out;

    // total threads = 8 * 64 * 128 * 64 = 4,194,304
    const long long total = 8LL * 64 * 128 * 64;
    const int block = 256;
    const int grid = (int)(total / block);  // 16384
    iwt_haar_kernel<<<grid, block, 0, stream>>>(x, out);
}